// Round 14
// baseline (69.507 us; speedup 1.0000x reference)
//
#include <hip/hip_runtime.h>

#define FC    75               // K*K*C floats per pixel
#define PXW   16               // pixels per wave (4 lanes per pixel)
#define SLABW 1200             // floats per wave slab (16*75) = 4.8 KB

#define AS1 __attribute__((address_space(1)))
#define AS3 __attribute__((address_space(3)))

typedef float f32x4 __attribute__((ext_vector_type(4), aligned(4)));

// 32768 blocks x 128 threads (2 independent waves, no barrier).
// Wave = 16 pixels, 4 lanes/pixel: lane quarter q -> taps 6q..6q+5
// (+ exec-masked tap 24 for q=3). Slab 4.8 KB/wave, 9.6 KB/block ->
// 16 blocks/CU = 32 waves/CU (HW max) — the wave-count lever measured:
// 4 waves=4.4, 8=4.85, 16=5.14 TB/s. Staging: NT (aux=2) width-16
// global_load_lds, 4 full + 1 exec-masked. launch_bounds(128,8) caps
// VGPR at 64 so occupancy is wave-slot-bound, not register-bound.

__global__ __launch_bounds__(128, 8)
void convolve_kernel(const float* __restrict__ img,
                     const float* __restrict__ filts,
                     float* __restrict__ out)
{
    __shared__ float slab[2 * SLABW];      // per-wave private halves

    const int tid  = threadIdx.x;
    const int wave = tid >> 6;
    const int lane = tid & 63;
    const int q    = lane & 3;             // tap quarter 0..3
    const int pxi  = lane >> 2;            // pixel within wave 0..15

    float* ws = slab + wave * SLABW;

    // bijective XCD-chunked swizzle (32768 % 8 == 0)
    const int bswz = ((int)blockIdx.x & 7) * 4096 + ((int)blockIdx.x >> 3);
    const int gpx0 = bswz * 32 + wave * PXW;   // first pixel of this wave

    // ---- stage 16 px * 75 floats = 300 float4 into the wave slab (NT) ----
    {
        const f32x4* src4 = (const f32x4*)(filts + (size_t)gpx0 * FC);
        #pragma unroll
        for (int j = 0; j < 4; ++j) {
            __builtin_amdgcn_global_load_lds(
                (const AS1 void*)(src4 + j * 64 + lane),
                (AS3 void*)(ws + j * 256),
                16, 0, /*aux=NT*/ 2);
        }
        if (lane < 44) {                    // tail: float4 256..299, exec-masked
            __builtin_amdgcn_global_load_lds(
                (const AS1 void*)(src4 + 256 + lane),
                (AS3 void*)(ws + 1024),
                16, 0, /*aux=NT*/ 2);
        }
    }
    asm volatile("s_waitcnt vmcnt(0)" ::: "memory");
    __builtin_amdgcn_sched_barrier(0);      // rule #18: ds_reads stay below wait

    // ---- compute: 4 lanes per pixel ----
    const int p  = gpx0 + pxi;
    const int b  = p >> 18;                 // / (512*512)
    const int hw = p & ((1 << 18) - 1);
    const int h  = hw >> 9;
    const int w  = hw & 511;

    // lane's filter base: pixel pxi, taps 6q.. -> dwords 18q..
    const float* fp   = ws + pxi * FC + q * 18;
    const float* imgb = img + (size_t)b * (512u * 512u * 3u);

    float a0 = 0.f, a1 = 0.f, a2 = 0.f;
    #pragma unroll
    for (int t = 0; t < 6; ++t) {
        const int T  = q * 6 + t;            // tap index 0..23 (runtime q)
        const int di = (T * 205) >> 10;      // floor(T/5), exact for T<25
        const int dj = T - 5 * di;
        const int hh = h + di - 2;
        const int ww = w + dj - 2;
        if (((unsigned)hh < 512u) && ((unsigned)ww < 512u)) {
            const float* px = imgb + (size_t)hh * 1536 + ww * 3;
            const float* fr = fp + t * 3;
            a0 += px[0] * fr[0];
            a1 += px[1] * fr[1];
            a2 += px[2] * fr[2];
        }
    }
    if (q == 3) {                            // tap 24 (di=4,dj=4), dwords 72..74
        const int hh = h + 2;
        const int ww = w + 2;
        if (((unsigned)hh < 512u) && ((unsigned)ww < 512u)) {
            const float* px = imgb + (size_t)hh * 1536 + ww * 3;
            const float* fr = fp + 18;       // 54 + 18 = 72
            a0 += px[0] * fr[0];
            a1 += px[1] * fr[1];
            a2 += px[2] * fr[2];
        }
    }

    // combine the 4 lanes of each pixel; lanes q==0 store 16 consecutive dwords
    float s = a0 + a1 + a2;
    s += __shfl_xor(s, 1, 64);
    s += __shfl_xor(s, 2, 64);
    if (q == 0) out[p] = s;
}

extern "C" void kernel_launch(void* const* d_in, const int* in_sizes, int n_in,
                              void* d_out, int out_size, void* d_ws, size_t ws_size,
                              hipStream_t stream)
{
    const float* img   = (const float*)d_in[0];   // [4,512,512,3]  f32
    const float* filts = (const float*)d_in[1];   // [4,512,512,75] f32
    float* out         = (float*)d_out;           // [4,512,512]    f32

    // 1,048,576 pixels / 32 per block = 32768 blocks of 128 threads
    convolve_kernel<<<32768, 128, 0, stream>>>(img, filts, out);
}

// Round 15
// 68.910 us; speedup vs baseline: 1.0087x; 1.0087x over previous
//
#include <hip/hip_runtime.h>

#define FC    75               // K*K*C floats per pixel
#define GPX   32               // pixels per group (2 lanes per pixel)
#define SLABF 2400             // 32 px * 75 floats = 9600 B -> 16 slabs/CU
#define GPB   4                // groups per block (sequential sawtooth)

#define AS1 __attribute__((address_space(1)))
#define AS3 __attribute__((address_space(3)))

typedef float f32x4 __attribute__((ext_vector_type(4), aligned(4)));

// R13 geometry (champion: 64.4 us, 16 waves/CU, 2 lanes/pixel, NT staging)
// + 4-group sequential loop per block:
//  - 8192 blocks -> 2 dispatch generations refill CU slots asynchronously,
//    breaking the lockstep stage/compute phase correlation of 32768 1-shot
//    blocks (decorrelated waves keep the CU read queue nonempty);
//  - stage(k+1) issued BEFORE store(k): store latency hides under the
//    staged loads. Slab overwrite is race-free: lgkmcnt(0)+sched_barrier
//    before stage guarantees all slab ds_reads retired (they are data-
//    dependencies of s anyway, so the wait is ~free).
// Strict sawtooth otherwise — no double-buffer (pipelines 0-for-3 here).

__global__ __launch_bounds__(64, 4)
void convolve_kernel(const float* __restrict__ img,
                     const float* __restrict__ filts,
                     float* __restrict__ out)
{
    __shared__ float slab[SLABF];

    const int lane = threadIdx.x;          // 0..63
    const int half = lane & 1;
    const int pxi  = lane >> 1;            // 0..31

    // bijective XCD-chunked swizzle (8192 % 8 == 0); 4 consecutive groups
    // per block keep pixel/img locality within the XCD's L2 slice.
    const int bswz = ((int)blockIdx.x & 7) * 1024 + ((int)blockIdx.x >> 3);
    const int gb   = bswz * GPB;

    // stage one group's 2400 filts floats (600 float4) into the slab, NT
    auto stage = [&](int g) {
        const f32x4* src4 = (const f32x4*)(filts + (size_t)g * (GPX * FC));
        #pragma unroll
        for (int j = 0; j < 9; ++j) {
            __builtin_amdgcn_global_load_lds(
                (const AS1 void*)(src4 + j * 64 + lane),
                (AS3 void*)(slab + j * 256),
                16, 0, /*aux=NT*/ 2);
        }
        if (lane < 24) {                    // tail: float4 576..599
            __builtin_amdgcn_global_load_lds(
                (const AS1 void*)(src4 + 576 + lane),
                (AS3 void*)(slab + 9 * 256),
                16, 0, /*aux=NT*/ 2);
        }
    };

    // tap tables: half0 -> taps 0..11, half1 -> taps 12..23 (tap 24 masked)
    const int DI0[12] = {0,0,0,0,0,1,1,1,1,1,2,2};
    const int DJ0[12] = {0,1,2,3,4,0,1,2,3,4,0,1};
    const int DI1[12] = {2,2,2,3,3,3,3,3,4,4,4,4};
    const int DJ1[12] = {2,3,4,0,1,2,3,4,0,1,2,3};

    stage(gb);                              // prologue

    #pragma unroll 1
    for (int k = 0; k < GPB; ++k) {
        asm volatile("s_waitcnt vmcnt(0)" ::: "memory");   // slab(k) landed
        __builtin_amdgcn_sched_barrier(0);  // rule #18: ds_reads stay below

        const int g  = gb + k;
        const int p  = g * GPX + pxi;       // 32 consecutive pixels, same row
        const int b  = p >> 18;             // / (512*512)
        const int hw = p & ((1 << 18) - 1);
        const int h  = hw >> 9;
        const int w  = hw & 511;

        const float* fp   = slab + pxi * FC + half * 36;
        const float* imgb = img + (size_t)b * (512u * 512u * 3u);

        float a0 = 0.f, a1 = 0.f, a2 = 0.f;
        #pragma unroll
        for (int t = 0; t < 12; ++t) {
            const int di = half ? DI1[t] : DI0[t];   // cndmask of constants
            const int dj = half ? DJ1[t] : DJ0[t];
            const int hh = h + di - 2;
            const int ww = w + dj - 2;
            if (((unsigned)hh < 512u) && ((unsigned)ww < 512u)) {
                const float* px = imgb + (size_t)hh * 1536 + ww * 3;
                const float* fr = fp + t * 3;
                a0 += px[0] * fr[0];
                a1 += px[1] * fr[1];
                a2 += px[2] * fr[2];
            }
        }
        if (half) {                          // tap 24 (di=4,dj=4), dwords 72..74
            const int hh = h + 2;
            const int ww = w + 2;
            if (((unsigned)hh < 512u) && ((unsigned)ww < 512u)) {
                const float* px = imgb + (size_t)hh * 1536 + ww * 3;
                const float* fr = fp + 36;   // 36 + 36 = dword 72
                a0 += px[0] * fr[0];
                a1 += px[1] * fr[1];
                a2 += px[2] * fr[2];
            }
        }

        // combine lane pair
        const float mine = a0 + a1 + a2;
        const float peer = __shfl_xor(mine, 1, 64);
        const float s    = mine + peer;

        // stage next group BEFORE the store: slab ds_reads all retired
        // (lgkmcnt(0) is ~free — they're data-deps of s), store latency
        // then hides under the 10 staged loads.
        if (k + 1 < GPB) {
            asm volatile("s_waitcnt lgkmcnt(0)" ::: "memory");
            __builtin_amdgcn_sched_barrier(0);
            stage(g + 1);
        }
        if (!half) out[p] = s;               // 32 lanes, 128B contiguous
    }
}

extern "C" void kernel_launch(void* const* d_in, const int* in_sizes, int n_in,
                              void* d_out, int out_size, void* d_ws, size_t ws_size,
                              hipStream_t stream)
{
    const float* img   = (const float*)d_in[0];   // [4,512,512,3]  f32
    const float* filts = (const float*)d_in[1];   // [4,512,512,75] f32
    float* out         = (float*)d_out;           // [4,512,512]    f32

    // 1,048,576 pixels / (32 px * 4 groups) = 8192 blocks of 64 threads
    convolve_kernel<<<8192, 64, 0, stream>>>(img, filts, out);
}

// Round 16
// 61.082 us; speedup vs baseline: 1.1379x; 1.1282x over previous
//
#include <hip/hip_runtime.h>

#define FC    75               // K*K*C floats per pixel
#define GPX   32               // pixels per group (2 lanes per pixel)
#define SLABF 2400             // 32 px * 75 floats = 9600 B -> 16 slabs/CU

#define AS1 __attribute__((address_space(1)))
#define AS3 __attribute__((address_space(3)))

typedef float f32x4 __attribute__((ext_vector_type(4), aligned(4)));

// R13 champion geometry (16 waves/CU, 2 lanes/pixel, NT staging) with ONE
// change: interior-group img loads vectorized. Each pixel's 5x16 window is
// loaded as 20 uniform f32x4 (both halves issue the same rows -> duplicate
// addresses coalesce), replacing ~37 scalar wave-loads (~250 TA-cyc) with
// 20 (~140 TA-cyc). FMA halves select their taps statically (divergent but
// VALU-cheap). Edge groups (g%16 == 0 or 15, wave-uniform) keep the proven
// scalar tap-table path. Regime-gate: R7's vectorization null was pre-NT
// (allocation-capped); at 5.14 TB/s the TA path is the candidate residual.

__global__ __launch_bounds__(64, 4)
void convolve_kernel(const float* __restrict__ img,
                     const float* __restrict__ filts,
                     float* __restrict__ out)
{
    __shared__ float slab[SLABF];

    const int lane = threadIdx.x;          // 0..63
    const int half = lane & 1;
    const int pxi  = lane >> 1;            // 0..31

    // bijective XCD-chunked swizzle (32768 % 8 == 0)
    const int g = ((int)blockIdx.x & 7) * 4096 + ((int)blockIdx.x >> 3);

    // ---- stage this group's 2400 filts floats (600 float4) into LDS, NT ----
    {
        const f32x4* src4 = (const f32x4*)(filts + (size_t)g * (GPX * FC));
        #pragma unroll
        for (int j = 0; j < 9; ++j) {
            __builtin_amdgcn_global_load_lds(
                (const AS1 void*)(src4 + j * 64 + lane),
                (AS3 void*)(slab + j * 256),
                16, 0, /*aux=NT*/ 2);
        }
        if (lane < 24) {                    // tail: float4 576..599
            __builtin_amdgcn_global_load_lds(
                (const AS1 void*)(src4 + 576 + lane),
                (AS3 void*)(slab + 9 * 256),
                16, 0, /*aux=NT*/ 2);
        }
    }
    asm volatile("s_waitcnt vmcnt(0)" ::: "memory");
    __builtin_amdgcn_sched_barrier(0);      // rule #18: ds_reads stay below wait

    // ---- compute: 2 lanes per pixel ----
    const int p  = g * GPX + pxi;           // 32 consecutive pixels, same row
    const int b  = p >> 18;                 // / (512*512)
    const int hw = p & ((1 << 18) - 1);
    const int h  = hw >> 9;
    const int w  = hw & 511;

    const float* fp   = slab + pxi * FC + half * 36;   // half0: dw 0.., half1: dw 36..
    const float* imgb = img + (size_t)b * (512u * 512u * 3u);

    const int w0 = (g * GPX) & 511;          // wave-uniform: 0,32,...,480
    float a0 = 0.f, a1 = 0.f, a2 = 0.f;

    if (w0 != 0 && w0 != 480) {
        // ---- fast path: full 5x16 window, 20 uniform vector loads ----
        f32x4 v[5][4];
        #pragma unroll
        for (int r = 0; r < 5; ++r)
            #pragma unroll
            for (int jj = 0; jj < 4; ++jj)
                v[r][jj] = (f32x4)0.f;

        const float* q0 = imgb + (w - 2) * 3;   // (w-2)*3+15 <= 1533 < 1536 ok
        #pragma unroll
        for (int r = 0; r < 5; ++r) {
            const int hh = h + r - 2;
            if ((unsigned)hh < 512u) {           // wave-uniform row guard
                const float* q = q0 + (size_t)hh * 1536;
                v[r][0] = *(const f32x4*)(q);
                v[r][1] = *(const f32x4*)(q + 4);
                v[r][2] = *(const f32x4*)(q + 8);
                v[r][3] = *(const f32x4*)(q + 12);
            }
        }

        // window float idx for tap (r,dj,c) = dj*3+c (0..14); filts dword = T*3+c
        if (!half) {
            #pragma unroll
            for (int T = 0; T < 12; ++T) {
                const int r = T / 5, dj = T % 5;
                const float* fr = fp + T * 3;
                a0 += v[r][(dj*3+0) >> 2][(dj*3+0) & 3] * fr[0];
                a1 += v[r][(dj*3+1) >> 2][(dj*3+1) & 3] * fr[1];
                a2 += v[r][(dj*3+2) >> 2][(dj*3+2) & 3] * fr[2];
            }
        } else {
            #pragma unroll
            for (int T = 12; T < 25; ++T) {
                const int r = T / 5, dj = T % 5;
                const float* fr = fp + (T - 12) * 3;   // base already +36
                a0 += v[r][(dj*3+0) >> 2][(dj*3+0) & 3] * fr[0];
                a1 += v[r][(dj*3+1) >> 2][(dj*3+1) & 3] * fr[1];
                a2 += v[r][(dj*3+2) >> 2][(dj*3+2) & 3] * fr[2];
            }
        }
    } else {
        // ---- edge path: R13's proven scalar tap tables ----
        const int DI0[12] = {0,0,0,0,0,1,1,1,1,1,2,2};
        const int DJ0[12] = {0,1,2,3,4,0,1,2,3,4,0,1};
        const int DI1[12] = {2,2,2,3,3,3,3,3,4,4,4,4};
        const int DJ1[12] = {2,3,4,0,1,2,3,4,0,1,2,3};
        #pragma unroll
        for (int t = 0; t < 12; ++t) {
            const int di = half ? DI1[t] : DI0[t];
            const int dj = half ? DJ1[t] : DJ0[t];
            const int hh = h + di - 2;
            const int ww = w + dj - 2;
            if (((unsigned)hh < 512u) && ((unsigned)ww < 512u)) {
                const float* px = imgb + (size_t)hh * 1536 + ww * 3;
                const float* fr = fp + t * 3;
                a0 += px[0] * fr[0];
                a1 += px[1] * fr[1];
                a2 += px[2] * fr[2];
            }
        }
        if (half) {                          // tap 24 (di=4,dj=4), dwords 72..74
            const int hh = h + 2;
            const int ww = w + 2;
            if (((unsigned)hh < 512u) && ((unsigned)ww < 512u)) {
                const float* px = imgb + (size_t)hh * 1536 + ww * 3;
                const float* fr = fp + 36;
                a0 += px[0] * fr[0];
                a1 += px[1] * fr[1];
                a2 += px[2] * fr[2];
            }
        }
    }

    // combine lane pair; even lanes store 32 consecutive dwords
    float s = a0 + a1 + a2;
    s += __shfl_xor(s, 1, 64);
    if (!half) out[p] = s;
}

extern "C" void kernel_launch(void* const* d_in, const int* in_sizes, int n_in,
                              void* d_out, int out_size, void* d_ws, size_t ws_size,
                              hipStream_t stream)
{
    const float* img   = (const float*)d_in[0];   // [4,512,512,3]  f32
    const float* filts = (const float*)d_in[1];   // [4,512,512,75] f32
    float* out         = (float*)d_out;           // [4,512,512]    f32

    // 1,048,576 pixels / 32 per block = 32768 blocks of 64 threads
    convolve_kernel<<<32768, 64, 0, stream>>>(img, filts, out);
}